// Round 2
// baseline (71.717 us; speedup 1.0000x reference)
//
#include <hip/hip_runtime.h>
#include <math.h>

// Sizes fixed by the reference.
#define SEQ   1024
#define BSZ   16
#define DIM   1024
#define SIDE  32
#define DPB   8         // d-channels per block (one b, 8 consecutive d)
#define THREADS 256     // 4 waves; each half-wave (32 lanes) owns one (b,d) image

__device__ __forceinline__ float sigmoidf_(float v) {
    return __builtin_amdgcn_rcpf(1.0f + __expf(-v));
}

// 2D SSM run as the recurrence directly on x (== causal conv with the impulse
// response == reference FFT path, by linearity/shift-invariance/causality):
//   v[i,j] = a2*h[i-1,j] + a1*v[i-1,j] + b2*x[i,j]
//   h[i,j] = a1*h[i,j-1] + a2*v[i,j-1] + b1*x[i,j]
//   y[i,j] = <h,C1*s> + <v,C2*s>;  out = silu(y + x*omega)
//
// Anti-diagonal wavefront: lane = row i, step t sweeps anti-diagonals,
// j = t - i.  h-update uses only the lane's own previous-step registers;
// v-update needs (h,v)[i-1,j], which lane i-1 published at step t-1 ->
// exactly ONE dependent shuffle layer per step (63 total) instead of a
// 6-deep shuffle chain per row (192 total) as in the scan formulation.
// Pre-start (j<0) lanes keep exactly-zero state automatically: all their
// inputs (xv, hu, vu) are zero, so their outputs remain zero.
__global__ __launch_bounds__(THREADS) void ssm2d_kernel(
    const float* __restrict__ x,
    const float* __restrict__ A1, const float* __restrict__ A2,
    const float* __restrict__ B1, const float* __restrict__ B2,
    const float* __restrict__ C1, const float* __restrict__ C2,
    const float* __restrict__ omega,
    float* __restrict__ out)
{
    __shared__ float xs[DPB * 1024];   // 32 KB -> 5 blocks/CU

    const int bx   = blockIdx.x;       // 0..2047
    const int b    = bx >> 7;          // 0..15
    const int dblk = bx & 127;         // 0..127
    const int d0   = dblk * DPB;
    const int t    = threadIdx.x;

    // ---- stage x into LDS, coalesced float4 (2048 float4s, 8 per thread) ----
    // Store pattern: per ds_write_b32, bank = s&31, 2 lanes/bank -> free.
    const float* xb = x + (size_t)b * DIM + d0;
    #pragma unroll
    for (int k = 0; k < 8; ++k) {
        int g = t + k * THREADS;       // 0..2047
        int s = g >> 1;
        int q = g & 1;                 // which float4 of the 8 dds
        const float4 v = *reinterpret_cast<const float4*>(
            xb + (size_t)s * (BSZ * DIM) + 4 * q);
        int dd0 = 4 * q;
        xs[(dd0 + 0) * 1024 + s] = v.x;
        xs[(dd0 + 1) * 1024 + s] = v.y;
        xs[(dd0 + 2) * 1024 + s] = v.z;
        xs[(dd0 + 3) * 1024 + s] = v.w;
    }

    // ---- per-lane coefficients for this lane's channel d ----
    const int lane = t & 63;
    const int w    = t >> 6;               // wave id 0..3
    const int dd   = 2 * w + (lane >> 5);  // image within block, 0..7
    const int i    = lane & 31;            // row owned by this lane
    const int d    = d0 + dd;

    float a1c[2], a2c[2], b1c[2], b2c[2], c1s[2], c2s[2];
    #pragma unroll
    for (int c = 0; c < 2; ++c) {
        a1c[c] = sigmoidf_(A1[d * 2 + c]) * 0.5f;
        a2c[c] = sigmoidf_(A2[d * 2 + c]) * 0.5f;
        b1c[c] = sigmoidf_(B1[d * 2 + c]) * 0.5f;
        b2c[c] = sigmoidf_(B2[d * 2 + c]) * 0.5f;
        c1s[c] = C1[d * 2 + c] * 0.70710678118654752f;  // * sqrt(1/NDIM)
        c2s[c] = C2[d * 2 + c] * 0.70710678118654752f;
    }
    const float om = omega[d];

    __syncthreads();

    // ---- anti-diagonal recurrence ----
    // Lane i touches LDS slot 31*i + tstep (always in [0,1023]); banks
    // (t - i) mod 32 are distinct per lane within a half-wave, 2-way across
    // the two half-waves -> conflict-free.
    float* xrow = &xs[dd * 1024 + 31 * i];
    const bool top = (i == 0);

    float h0 = 0.f, h1 = 0.f, v0 = 0.f, v1 = 0.f;  // published state (h,v)[i, j]

    #pragma unroll 7
    for (int ts = 0; ts < 63; ++ts) {
        // pull (h,v)[i-1, j] from lane i-1 (its step ts-1 result)
        float su;
        su = __shfl_up(h0, 1, 32);  const float hu0 = top ? 0.f : su;
        su = __shfl_up(h1, 1, 32);  const float hu1 = top ? 0.f : su;
        su = __shfl_up(v0, 1, 32);  const float vu0 = top ? 0.f : su;
        su = __shfl_up(v1, 1, 32);  const float vu1 = top ? 0.f : su;

        const int   j     = ts - i;
        const bool  valid = ((unsigned)j < 32u);
        const float xraw  = xrow[ts];
        const float xv    = valid ? xraw : 0.f;

        // h[i,j] from own previous (h,v)[i,j-1]; v[i,j] from neighbor
        const float hn0 = fmaf(a1c[0], h0, fmaf(a2c[0], v0, b1c[0] * xv));
        const float hn1 = fmaf(a1c[1], h1, fmaf(a2c[1], v1, b1c[1] * xv));
        const float vn0 = fmaf(a2c[0], hu0, fmaf(a1c[0], vu0, b2c[0] * xv));
        const float vn1 = fmaf(a2c[1], hu1, fmaf(a1c[1], vu1, b2c[1] * xv));

        float y = hn0 * c1s[0];
        y = fmaf(hn1, c1s[1], y);
        y = fmaf(vn0, c2s[0], y);
        y = fmaf(vn1, c2s[1], y);
        const float z = fmaf(xv, om, y);
        const float o = z * sigmoidf_(z);

        if (valid) xrow[ts] = o;   // each slot read exactly once (this step)

        h0 = hn0; h1 = hn1; v0 = vn0; v1 = vn1;
    }

    __syncthreads();

    // ---- coalesced float4 store-out (mirror of staging) ----
    float* ob = out + (size_t)b * DIM + d0;
    #pragma unroll
    for (int k = 0; k < 8; ++k) {
        int g = t + k * THREADS;
        int s = g >> 1;
        int q = g & 1;
        int dd0 = 4 * q;
        float4 v;
        v.x = xs[(dd0 + 0) * 1024 + s];
        v.y = xs[(dd0 + 1) * 1024 + s];
        v.z = xs[(dd0 + 2) * 1024 + s];
        v.w = xs[(dd0 + 3) * 1024 + s];
        *reinterpret_cast<float4*>(ob + (size_t)s * (BSZ * DIM) + 4 * q) = v;
    }
}

extern "C" void kernel_launch(void* const* d_in, const int* in_sizes, int n_in,
                              void* d_out, int out_size, void* d_ws, size_t ws_size,
                              hipStream_t stream) {
    const float* x     = (const float*)d_in[0];
    const float* A1    = (const float*)d_in[1];
    const float* A2    = (const float*)d_in[2];
    const float* B1    = (const float*)d_in[3];
    const float* B2    = (const float*)d_in[4];
    const float* C1    = (const float*)d_in[5];
    const float* C2    = (const float*)d_in[6];
    const float* omega = (const float*)d_in[7];
    float* out = (float*)d_out;

    dim3 grid(BSZ * (DIM / DPB));   // 16 * 128 = 2048 blocks
    dim3 block(THREADS);
    hipLaunchKernelGGL(ssm2d_kernel, grid, block, 0, stream,
                       x, A1, A2, B1, B2, C1, C2, omega, out);
}

// Round 3
// 52.256 us; speedup vs baseline: 1.3724x; 1.3724x over previous
//
#include <hip/hip_runtime.h>
#include <math.h>

// Sizes fixed by the reference.
#define SEQ   1024
#define BSZ   16
#define DIM   1024
#define SIDE  32
#define DPB   16        // d-channels per block (64B global granule -> clean fetch)
#define THREADS 512     // 8 waves; each half-wave (32 lanes) owns one (b,d) image
#define NLDS  (DPB * 1024 + THREADS)   // image buffer + per-thread dump slots

__device__ __forceinline__ float sigmoidf_(float v) {
    return __builtin_amdgcn_rcpf(1.0f + __expf(-v));
}

// lane n <- lane n-1 across the full wave64 (lane 0 -> 0.0f), pure VALU:
// v_mov_b32_dpp wave_shr:1  (DPP ctrl 0x138; gfx9-family op, present on CDNA).
// ~2cy vs ~120cy for the ds_bpermute that __shfl_up generates.
__device__ __forceinline__ float dpp_up1(float v) {
    return __int_as_float(__builtin_amdgcn_update_dpp(
        0, __float_as_int(v), 0x138, 0xF, 0xF, true));
}

// 2D SSM run as the recurrence directly on x (== causal conv with the impulse
// response == reference FFT path, by linearity/shift-invariance/causality):
//   v[i,j] = a2*h[i-1,j] + a1*v[i-1,j] + b2*x[i,j]
//   h[i,j] = a1*h[i,j-1] + a2*v[i,j-1] + b1*x[i,j]
//   y[i,j] = <h,C1*s> + <v,C2*s>;  out = silu(y + x*omega)
//
// Anti-diagonal wavefront: lane = row i, step ts sweeps anti-diagonals,
// j = ts - i.  h-update uses only the lane's own previous-step registers;
// v-update needs (h,v)[i-1,j] = what lane i-1 produced at step ts-1, fetched
// with ONE wave_shr:1 DPP (VALU) per state word -> the serial chain is pure
// VALU (~6 ops deep), no LDS latency on the critical path.
__global__ __launch_bounds__(THREADS) void ssm2d_kernel(
    const float* __restrict__ x,
    const float* __restrict__ A1, const float* __restrict__ A2,
    const float* __restrict__ B1, const float* __restrict__ B2,
    const float* __restrict__ C1, const float* __restrict__ C2,
    const float* __restrict__ omega,
    float* __restrict__ out)
{
    __shared__ float xs[NLDS];   // 67.6 KB -> 2 blocks/CU

    const int bx   = blockIdx.x;       // 0..1023
    const int b    = bx >> 6;          // 0..15
    const int dblk = bx & 63;          // 0..63
    const int d0   = dblk * DPB;
    const int t    = threadIdx.x;

    // ---- stage x into LDS, coalesced float4 (4096 float4s, 8 per thread) ----
    const float* xb = x + (size_t)b * DIM + d0;
    #pragma unroll
    for (int k = 0; k < 8; ++k) {
        int g = t + k * THREADS;       // 0..4095
        int s = g >> 2;
        int q = g & 3;                 // which float4 of the 16 dds
        const float4 v = *reinterpret_cast<const float4*>(
            xb + (size_t)s * (BSZ * DIM) + 4 * q);
        int dd0 = 4 * q;
        xs[(dd0 + 0) * 1024 + s] = v.x;
        xs[(dd0 + 1) * 1024 + s] = v.y;
        xs[(dd0 + 2) * 1024 + s] = v.z;
        xs[(dd0 + 3) * 1024 + s] = v.w;
    }

    // ---- per-lane coefficients for this lane's channel d ----
    const int lane = t & 63;
    const int w    = t >> 6;               // wave id 0..7
    const int dd   = 2 * w + (lane >> 5);  // image within block, 0..15
    const int i    = lane & 31;            // row owned by this lane
    const int d    = d0 + dd;

    float a1c[2], a2c[2], b1c[2], b2c[2], c1s[2], c2s[2];
    #pragma unroll
    for (int c = 0; c < 2; ++c) {
        a1c[c] = sigmoidf_(A1[d * 2 + c]) * 0.5f;
        a2c[c] = sigmoidf_(A2[d * 2 + c]) * 0.5f;
        b1c[c] = sigmoidf_(B1[d * 2 + c]) * 0.5f;
        b2c[c] = sigmoidf_(B2[d * 2 + c]) * 0.5f;
        c1s[c] = C1[d * 2 + c] * 0.70710678118654752f;  // * sqrt(1/NDIM)
        c2s[c] = C2[d * 2 + c] * 0.70710678118654752f;
    }
    const float om = omega[d];

    __syncthreads();

    // ---- anti-diagonal recurrence ----
    // Lane i's reads/writes are at flat addr 31*i + ts: banks (ts - i) mod 32
    // distinct per half-wave, 2-way across half-waves (free). All loop LDS ops
    // are base + compile-time immediate (full unroll).
    const int  ibase   = dd * 1024 + 31 * i;
    const int  dumpidx = DPB * 1024 + t;   // private dump slot for invalid steps
    const bool nottop  = (i != 0);         // lanes 0 and 32 take 0 from the DPP

    float h0 = 0.f, h1 = 0.f, v0 = 0.f, v1 = 0.f;
    float xr = xs[ibase];                  // prefetch ts=0

    #pragma unroll
    for (int ts = 0; ts < 63; ++ts) {
        // (h,v)[i-1, j] from lane i-1 (its step ts-1 result) — pure VALU
        float hu0 = dpp_up1(h0); hu0 = nottop ? hu0 : 0.f;
        float hu1 = dpp_up1(h1); hu1 = nottop ? hu1 : 0.f;
        float vu0 = dpp_up1(v0); vu0 = nottop ? vu0 : 0.f;
        float vu1 = dpp_up1(v1); vu1 = nottop ? vu1 : 0.f;

        const bool  valid = ((unsigned)(ts - i) < 32u);
        const float xv    = valid ? xr : 0.f;
        // prefetch next step's x BEFORE this step's aliasing write
        float xr_n = 0.f;
        if (ts < 62) xr_n = xs[ibase + ts + 1];

        const float hn0 = fmaf(a1c[0], h0, fmaf(a2c[0], v0, b1c[0] * xv));
        const float hn1 = fmaf(a1c[1], h1, fmaf(a2c[1], v1, b1c[1] * xv));
        const float vn0 = fmaf(a2c[0], hu0, fmaf(a1c[0], vu0, b2c[0] * xv));
        const float vn1 = fmaf(a2c[1], hu1, fmaf(a1c[1], vu1, b2c[1] * xv));

        float y = hn0 * c1s[0];
        y = fmaf(hn1, c1s[1], y);
        y = fmaf(vn0, c2s[0], y);
        y = fmaf(vn1, c2s[1], y);
        const float z = fmaf(xv, om, y);
        const float o = z * sigmoidf_(z);

        // address-select instead of exec-mask predication: invalid lanes
        // write to a private dump slot (no divergence, unconditional store)
        const int widx = valid ? (ibase + ts) : dumpidx;
        xs[widx] = o;

        h0 = hn0; h1 = hn1; v0 = vn0; v1 = vn1;
        xr = xr_n;
    }

    __syncthreads();

    // ---- coalesced float4 store-out (mirror of staging) ----
    float* ob = out + (size_t)b * DIM + d0;
    #pragma unroll
    for (int k = 0; k < 8; ++k) {
        int g = t + k * THREADS;
        int s = g >> 2;
        int q = g & 3;
        int dd0 = 4 * q;
        float4 v;
        v.x = xs[(dd0 + 0) * 1024 + s];
        v.y = xs[(dd0 + 1) * 1024 + s];
        v.z = xs[(dd0 + 2) * 1024 + s];
        v.w = xs[(dd0 + 3) * 1024 + s];
        *reinterpret_cast<float4*>(ob + (size_t)s * (BSZ * DIM) + 4 * q) = v;
    }
}

extern "C" void kernel_launch(void* const* d_in, const int* in_sizes, int n_in,
                              void* d_out, int out_size, void* d_ws, size_t ws_size,
                              hipStream_t stream) {
    const float* x     = (const float*)d_in[0];
    const float* A1    = (const float*)d_in[1];
    const float* A2    = (const float*)d_in[2];
    const float* B1    = (const float*)d_in[3];
    const float* B2    = (const float*)d_in[4];
    const float* C1    = (const float*)d_in[5];
    const float* C2    = (const float*)d_in[6];
    const float* omega = (const float*)d_in[7];
    float* out = (float*)d_out;

    dim3 grid(BSZ * (DIM / DPB));   // 16 * 64 = 1024 blocks
    dim3 block(THREADS);
    hipLaunchKernelGGL(ssm2d_kernel, grid, block, 0, stream,
                       x, A1, A2, B1, B2, C1, C2, omega, out);
}